// Round 1
// baseline (217.081 us; speedup 1.0000x reference)
//
#include <hip/hip_runtime.h>

#define HH 512
#define WW 512
#define ROWS 8
#define CH_STRIDE (HH*WW)
#define IMG_STRIDE (3*HH*WW)
#define NCHUNK (HH/ROWS)   // 64

// quantize one channel value: floor(clip(v*255, 0, 255))
__device__ __forceinline__ float quant(float v) {
    return floorf(fminf(fmaxf(v * 255.0f, 0.0f), 255.0f));
}

// compute 4 gray pixels (rounded, cv2 RGB2GRAY weights) at row gr, cols 4*wq..4*wq+3
__device__ __forceinline__ float4 gray4(const float* __restrict__ img, int gr, int wq) {
    const float4 r = reinterpret_cast<const float4*>(img + 0 * CH_STRIDE + gr * WW)[wq];
    const float4 g = reinterpret_cast<const float4*>(img + 1 * CH_STRIDE + gr * WW)[wq];
    const float4 b = reinterpret_cast<const float4*>(img + 2 * CH_STRIDE + gr * WW)[wq];
    float4 o;
    o.x = rintf(0.299f * quant(r.x) + 0.587f * quant(g.x) + 0.114f * quant(b.x));
    o.y = rintf(0.299f * quant(r.y) + 0.587f * quant(g.y) + 0.114f * quant(b.y));
    o.z = rintf(0.299f * quant(r.z) + 0.587f * quant(g.z) + 0.114f * quant(b.z));
    o.w = rintf(0.299f * quant(r.w) + 0.587f * quant(g.w) + 0.114f * quant(b.w));
    return o;
}

__global__ __launch_bounds__(256, 4) void sobel_loss_kernel(
    const float* __restrict__ pred, const float* __restrict__ gt_,
    float* __restrict__ out)
{
    // gray tiles for both images: (ROWS+2) x 512 floats each = 20 KiB each
    __shared__ float gp[(ROWS + 2) * WW];
    __shared__ float gq[(ROWS + 2) * WW];

    const int blk   = blockIdx.x;
    const int b     = blk >> 6;        // /NCHUNK
    const int chunk = blk & (NCHUNK - 1);
    const int r0    = chunk * ROWS;

    const float* P = pred + (size_t)b * IMG_STRIDE;
    const float* T = gt_  + (size_t)b * IMG_STRIDE;

    // ---- fill gray LDS: rows r0-1 .. r0+ROWS (BORDER_REFLECT_101) ----
    // (ROWS+2)*WW/4 = 1280 float4 items, 256 threads -> 5 iters
    float4* gp4 = reinterpret_cast<float4*>(gp);
    float4* gq4 = reinterpret_cast<float4*>(gq);
    for (int i4 = threadIdx.x; i4 < (ROWS + 2) * (WW / 4); i4 += 256) {
        const int lr = i4 >> 7;          // / (WW/4)
        const int wq = i4 & 127;
        int gr = r0 - 1 + lr;
        gr = (gr < 0) ? 1 : ((gr > HH - 1) ? 2 * (HH - 1) - gr : gr);
        gp4[i4] = gray4(P, gr, wq);
        gq4[i4] = gray4(T, gr, wq);
    }
    __syncthreads();

    // ---- sobel + |diff| accumulate ----
    float acc = 0.0f;
    for (int idx = threadIdx.x; idx < ROWS * WW; idx += 256) {
        const int lr = (idx >> 9) + 1;   // LDS row 1..ROWS
        const int w  = idx & (WW - 1);
        const int wm = (w == 0) ? 1 : w - 1;
        const int wp = (w == WW - 1) ? WW - 2 : w + 1;

        const float sxp = fabsf(gp[lr * WW + wp] - gp[lr * WW + wm]);
        const float syp = fabsf(gp[(lr + 1) * WW + w] - gp[(lr - 1) * WW + w]);
        const float sp  = rintf(0.5f * sxp + 0.5f * syp);

        const float sxt = fabsf(gq[lr * WW + wp] - gq[lr * WW + wm]);
        const float syt = fabsf(gq[(lr + 1) * WW + w] - gq[(lr - 1) * WW + w]);
        const float st  = rintf(0.5f * sxt + 0.5f * syt);

        acc += fabsf(sp - st);
    }

    // ---- reduce: wave shuffle, then cross-wave via reused LDS ----
    for (int off = 32; off > 0; off >>= 1)
        acc += __shfl_down(acc, off, 64);

    __syncthreads();                    // all LDS reads done; safe to reuse gp
    const int lane = threadIdx.x & 63;
    const int wid  = threadIdx.x >> 6;
    if (lane == 0) gp[wid] = acc;
    __syncthreads();
    if (threadIdx.x == 0) {
        const float s = gp[0] + gp[1] + gp[2] + gp[3];
        // mean over 32*512*512 elements, then /255
        atomicAdd(out, s * (1.0f / (255.0f * 32.0f * 512.0f * 512.0f)));
    }
}

extern "C" void kernel_launch(void* const* d_in, const int* in_sizes, int n_in,
                              void* d_out, int out_size, void* d_ws, size_t ws_size,
                              hipStream_t stream) {
    const float* y_pred = (const float*)d_in[0];
    const float* y_true = (const float*)d_in[1];
    float* out = (float*)d_out;

    // harness re-poisons d_out with 0xAA before every timed launch
    hipMemsetAsync(out, 0, out_size * sizeof(float), stream);

    const int nblk = 32 * NCHUNK;   // one block per (batch, 8-row strip)
    sobel_loss_kernel<<<nblk, 256, 0, stream>>>(y_pred, y_true, out);
}